// Round 11
// baseline (278.359 us; speedup 1.0000x reference)
//
#include <hip/hip_runtime.h>

// ValueDVHLoss via the Wasserstein/CDF identity.
// R11: every intra-hist theory is exhausted (R5-R10: MLP, occupancy, banks,
// bins, atomic count all varied 3-12x with no effect; hist ~45-55us floor).
// Last controllable term: inter-dispatch gaps. Fuse to ONE kernel:
// per-block MAGIC completion flags (poison 0xAA != MAGIC -> no init needed,
// no init race), workers = blocks 0..23 spin on all 1024 flags (deadlock-
// safe without co-residency: non-workers exit and free slots), each worker
// reduces+scans its segment, worker 0 finalizes via 24 S-flags.
// hist core identical to R10 (passed, absmax 0.0).

#define NBINS 1024
#define NB1   (NBINS - 1)
#define RROI  6
#define BPAT  4
#define NSEG  24
#define VVOX  1048576            // voxels per patient (C=1)
#define BLKP  256                // hist blocks per patient
#define GRID1 (BPAT * BLKP)      // 1024 blocks
#define CHUNK (VVOX / BLKP)      // 4096 voxels per block
#define TILE  1024               // voxels per DMA tile
#define NTILE (CHUNK / TILE)     // 4
#define HW    (NBINS / 2)        // 512 packed words per (block,roi)
#define MAGIC 0x5D5D5D5D         // != 0xAAAAAAAA poison, != 0

// tile[] int layout: pred 0..1023, tgt 1024..2047, masks 2048..3583,
// counts 3584..3589 (NOT overwritten by DMA)
#define T_PRED 0
#define T_TGT  1024
#define T_MSK  2048
#define T_CNT  3584

// ws layout (int indices)
#define PART_I  0
#define PART_N  (GRID1 * RROI * HW)       // 3,145,728 ints (12.6 MB)
#define CNT6_I  (PART_I + PART_N)
#define CNT6_N  (GRID1 * RROI)            // 6144
#define FLAG_I  (CNT6_I + CNT6_N)         // 1024 per-block done flags
#define SFLAG_I (FLAG_I + GRID1)          // 24 per-segment done flags
#define S_I     (SFLAG_I + NSEG)          // 24 floats
#define DEN_I   (S_I + NSEG)              // 24 ints

typedef __attribute__((address_space(1))) const void glb_t;
typedef __attribute__((address_space(3))) void lds_t;

__global__ __launch_bounds__(512) void dvh_fused(
    const float* __restrict__ pred, const float* __restrict__ tgt,
    const void* __restrict__ mask, int* __restrict__ ws,
    float* __restrict__ out) {
  __shared__ unsigned long long hp[NBINS];      // 8 KB pred hist
  __shared__ unsigned long long ht[NBINS];      // 8 KB tgt hist
  __shared__ __align__(16) int tile[3590];      // 14 KB tile + counts
  __shared__ int wsum2[8];
  __shared__ unsigned long long lsum2[8];
  __shared__ int dsum2[8];
  const int tid  = threadIdx.x;
  const int lane = tid & 63;
  const int wid  = tid >> 6;            // 8 waves
  const int flat = blockIdx.x;          // 0..1023
  const int b    = flat >> 8;           // patient
  const int nb   = flat & (BLKP - 1);
  const int v0   = nb * CHUNK;

  const unsigned int* mwp = (const unsigned int*)mask;
  const int byteLayout = __any(mwp[tid] > 1u);

  for (int i = tid; i < NBINS; i += 512) { hp[i] = 0ull; ht[i] = 0ull; }
  if (tid < 6) tile[T_CNT + tid] = 0;

  unsigned long long cpack = 0ull;      // per-thread packed mask counts

#define VOX(A, PP, GG)                                                       \
  {                                                                          \
    int bp = min((int)((PP) * 1024.0f), NB1);                                \
    int bg = min((int)((GG) * 1024.0f), NB1);                                \
    atomicAdd(&hp[bp], (A)); atomicAdd(&ht[bg], (A));                        \
    cpack += (A);                                                            \
  }

  if (byteLayout) {
    const char* pbase = (const char*)(pred + (size_t)b * VVOX + v0);
    const char* gbase = (const char*)(tgt  + (size_t)b * VVOX + v0);
    const char* mbase = (const char*)mask;

    for (int t = 0; t < NTILE; t++) {
      // DMA 14 x 1KB slices: 0-3 pred, 4-7 tgt, 8-13 masks (roi r = j-8)
      for (int j = wid; j < 14; j += 8) {
        const char* src; int dst;
        if (j < 4)      { src = pbase + t * 4096 + j * 1024;       dst = (T_PRED * 4) + j * 1024; }
        else if (j < 8) { src = gbase + t * 4096 + (j - 4) * 1024; dst = (T_TGT * 4) + (j - 4) * 1024; }
        else {
          int r = j - 8;
          src = mbase + (size_t)(r * BPAT + b) * VVOX + v0 + t * TILE;
          dst = (T_MSK * 4) + r * 1024;
        }
        __builtin_amdgcn_global_load_lds(
            (glb_t*)(src + lane * 16),
            (lds_t*)((char*)tile + dst), 16, 0, 0);
      }
      __syncthreads();   // drain DMA (hist-zero also visible on iter 0)

      // 2 voxels per thread: tile voxels 2*tid, 2*tid+1
      float2 pv = *(const float2*)&tile[T_PRED + 2 * tid];
      float2 gv = *(const float2*)&tile[T_TGT + 2 * tid];
      unsigned md[RROI];
#pragma unroll
      for (int r = 0; r < RROI; r++)
        md[r] = *(const unsigned*)&tile[T_MSK + r * 256 + (tid >> 1)];
      const int sh = (tid & 1) << 4;    // byte pair within the dword
      unsigned long long a0 = 0ull, a1 = 0ull;
#pragma unroll
      for (int r = 0; r < RROI; r++) {
        a0 |= (unsigned long long)((md[r] >> sh) & 1u) << (10 * r);
        a1 |= (unsigned long long)((md[r] >> (sh + 8)) & 1u) << (10 * r);
      }
      VOX(a0, pv.x, gv.x)
      VOX(a1, pv.y, gv.y)
      __syncthreads();   // protect tile before next DMA overwrites
    }
  } else {  // int32 masks — correctness-only path, direct loads
    __syncthreads();
    const int* mi = (const int*)mask;
    const float4* p4 = (const float4*)(pred + (size_t)b * VVOX + v0);
    const float4* g4 = (const float4*)(tgt  + (size_t)b * VVOX + v0);
    for (int pk = tid; pk < CHUNK / 4; pk += 512) {
      float4 pv = p4[pk], gv = g4[pk];
      unsigned long long a0 = 0, a1 = 0, a2 = 0, a3 = 0;
#pragma unroll
      for (int r = 0; r < RROI; r++) {
        int4 mm = ((const int4*)(mi + (size_t)(r * BPAT + b) * VVOX + v0))[pk];
        a0 |= (unsigned long long)(mm.x & 1) << (10 * r);
        a1 |= (unsigned long long)(mm.y & 1) << (10 * r);
        a2 |= (unsigned long long)(mm.z & 1) << (10 * r);
        a3 |= (unsigned long long)(mm.w & 1) << (10 * r);
      }
      VOX(a0, pv.x, gv.x)
      VOX(a1, pv.y, gv.y)
      VOX(a2, pv.z, gv.z)
      VOX(a3, pv.w, gv.w)
    }
    __syncthreads();
  }
#undef VOX

  // count merge: wave-reduce packed u64 (fields <= 512, 10-bit safe)
  for (int off = 32; off > 0; off >>= 1)
    cpack += __shfl_down(cpack, off, 64);
  if (lane == 0) {
#pragma unroll
    for (int r = 0; r < RROI; r++)
      atomicAdd(&tile[T_CNT + r], (int)((cpack >> (10 * r)) & 1023ull));
  }
  __syncthreads();

  // write signed int16 diffs (pred-tgt), 2 bins per int
  for (int idx = tid; idx < RROI * HW; idx += 512) {   // 6 iters
    int r = idx >> 9, wd = idx & (HW - 1);
    int s = 10 * r;
    int d0 = (int)((hp[2 * wd] >> s) & 1023ull) -
             (int)((ht[2 * wd] >> s) & 1023ull);
    int d1 = (int)((hp[2 * wd + 1] >> s) & 1023ull) -
             (int)((ht[2 * wd + 1] >> s) & 1023ull);
    ws[PART_I + (size_t)(flat * RROI + r) * HW + wd] = (d0 & 0xffff) | (d1 << 16);
  }
  if (tid < RROI)
    ws[CNT6_I + flat * RROI + tid] = tile[T_CNT + tid];

  // ---- completion flag (init-free: poison 0xAA != MAGIC) -----------------
  __syncthreads();
  if (tid == 0) {
    __threadfence();
    __hip_atomic_store(&ws[FLAG_I + flat], MAGIC, __ATOMIC_RELEASE,
                       __HIP_MEMORY_SCOPE_AGENT);
  }
  if (flat >= NSEG) return;   // non-workers exit, freeing CU slots

  // ---- worker: one block per segment -------------------------------------
  const int seg = flat, r = seg >> 2, bb = seg & 3;
  {
    const int i0 = 2 * tid, i1 = 2 * tid + 1;
    while (__hip_atomic_load(&ws[FLAG_I + i0], __ATOMIC_RELAXED,
                             __HIP_MEMORY_SCOPE_AGENT) != MAGIC ||
           __hip_atomic_load(&ws[FLAG_I + i1], __ATOMIC_RELAXED,
                             __HIP_MEMORY_SCOPE_AGENT) != MAGIC)
      __builtin_amdgcn_s_sleep(8);
  }
  __syncthreads();
  __threadfence();   // acquire: partials/CNT6 of all blocks now visible

  // reduce 256 partial rows; this thread owns bins 2*tid, 2*tid+1
  int s0 = 0, s1 = 0;
  const int* prow = ws + PART_I + (size_t)(bb * BLKP * RROI + r) * HW + tid;
#pragma unroll 8
  for (int nbk = 0; nbk < BLKP; nbk++) {
    int v = prow[(size_t)nbk * RROI * HW];
    s0 += (int)(short)(v & 0xffff);
    s1 += (v >> 16);
  }

  // block-wide scan over 512 thread totals
  int tot = s0 + s1;
  int v = tot;
  for (int off = 1; off < 64; off <<= 1) {
    int u = __shfl_up(v, off, 64);
    if (lane >= off) v += u;
  }
  if (lane == 63) wsum2[wid] = v;
  int dv = (tid < BLKP) ? ws[CNT6_I + (bb * BLKP + tid) * RROI + r] : 0;
  for (int off = 32; off > 0; off >>= 1) dv += __shfl_down(dv, off, 64);
  if (lane == 0) dsum2[wid] = dv;
  __syncthreads();
  int woff = 0;
  for (int w = 0; w < wid; w++) woff += wsum2[w];
  const int excl = woff + v - tot;
  int c0 = excl + s0, c1 = excl + tot;
  unsigned long long acc = (unsigned long long)(c0 < 0 ? -c0 : c0) +
                           (unsigned long long)(c1 < 0 ? -c1 : c1);
  for (int off = 32; off > 0; off >>= 1) acc += __shfl_down(acc, off, 64);
  if (lane == 0) lsum2[wid] = acc;
  __syncthreads();

  if (tid == 0) {
    unsigned long long a = 0; int d = 0;
    for (int w = 0; w < 8; w++) { a += lsum2[w]; d += dsum2[w]; }
    ((float*)ws)[S_I + seg] = (float)((double)a * (52.0 / (double)NBINS));
    ws[DEN_I + seg] = d;
    __threadfence();
    __hip_atomic_store(&ws[SFLAG_I + seg], MAGIC, __ATOMIC_RELEASE,
                       __HIP_MEMORY_SCOPE_AGENT);
  }

  // ---- worker 0 finalizes after all 24 segments --------------------------
  if (seg == 0) {
    if (tid < NSEG) {
      while (__hip_atomic_load(&ws[SFLAG_I + tid], __ATOMIC_RELAXED,
                               __HIP_MEMORY_SCOPE_AGENT) != MAGIC)
        __builtin_amdgcn_s_sleep(8);
    }
    __syncthreads();
    __threadfence();
    if (tid == 0) {
      float total = 0.f; int nv = 0;
      for (int pb = 0; pb < BPAT; pb++) {
        float num = 0.f; long long dd = 0;
        for (int rr = 0; rr < RROI; rr++) {
          num += __hip_atomic_load(&((float*)ws)[S_I + rr * BPAT + pb],
                                   __ATOMIC_RELAXED, __HIP_MEMORY_SCOPE_AGENT);
          dd  += __hip_atomic_load(&ws[DEN_I + rr * BPAT + pb],
                                   __ATOMIC_RELAXED, __HIP_MEMORY_SCOPE_AGENT);
        }
        if (dd > 0) { total += num / fmaxf((float)dd, 1.f); nv++; }
      }
      out[0] = total / (float)(nv > 0 ? nv : 1);
    }
  }
}

extern "C" void kernel_launch(void* const* d_in, const int* in_sizes, int n_in,
                              void* d_out, int out_size, void* d_ws,
                              size_t ws_size, hipStream_t stream) {
  const float* pred = (const float*)d_in[0];
  const float* tgt  = (const float*)d_in[1];
  const void* mask  = d_in[2];
  int* ws = (int*)d_ws;   // needs ~12.8 MB; d_ws is 384 MiB

  dvh_fused<<<GRID1, 512, 0, stream>>>(pred, tgt, mask, ws, (float*)d_out);
}

// Round 12
// 189.677 us; speedup vs baseline: 1.4675x; 1.4675x over previous
//
#include <hip/hip_runtime.h>

// ValueDVHLoss via the Wasserstein/CDF identity:
//   sum_i |a_(i) - b_(i)| = integral |#{a<=t} - #{b<=t}| dt
// R12 = exact revert to R9, the best-measured variant (190.7us total).
// R11's single-kernel fusion regressed (VGPR collapsed to 32, spin-flag tail
// serialized at 24-block parallelism: in-kernel 162us vs ~60us sum of parts).
// R9 structure: DMA-staged (global_load_lds, no VGPR round-trip) per-chunk
// histogram over all 6 ROIs, NBINS=1024, 512 blocks; then a 96-block
// reduce+scan dispatch. Session evidence: hist ~50us floor is invariant to
// load MLP, occupancy, bank conflicts, bin count (16K->1K), atomic count
// (25.2M->8.4M lane-ops) and width -- latency-bound, all pipes <20%.

#define NBINS 1024
#define NB1   (NBINS - 1)
#define RROI  6
#define BPAT  4
#define NSEG  24                 // seg = r*BPAT + b
#define VVOX  1048576            // voxels per patient (C=1)
#define BLKP  128                // hist blocks per patient
#define GRID1 (BPAT * BLKP)      // 512 blocks = 2/CU
#define CHUNK (VVOX / BLKP)      // 8192 voxels per block
#define TILE  2048               // voxels per DMA tile
#define NTILE (CHUNK / TILE)     // 4
#define HW    (NBINS / 2)        // 512 packed words per (block,roi)

// LDS layout (int indices): hist 6x1024 @ 0 (24KB), tile buf @ 6144 (28KB):
// pred floats @6144, tgt @8192, mask bytes @10240 + roi*512 ints
#define LDS_INTS 13312
#define PRED_I 6144
#define TGT_I  8192
#define MSK_I  10240
#define BUF_I  6144              // reused for count merge after last tile

// ws layout (int indices)
#define PART_I 0
#define PART_N (GRID1 * RROI * HW)        // 1,572,864 ints (6.3 MB)
#define CNT6_I (PART_I + PART_N)
#define CNT6_N (GRID1 * RROI)             // 3072
#define FH_I   (CNT6_I + CNT6_N)
#define FH_N   (NSEG * NBINS)             // 24576
#define DONE_I (FH_I + FH_N)              // 24
#define SEGD_I (DONE_I + NSEG)            // 1
#define ZERO_I FH_I
#define ZERO_N (FH_N + NSEG + 1)          // 24601 (zeroed by hist blocks)
#define S_I    (SEGD_I + 1)               // 24 floats
#define DEN_I  (S_I + NSEG)               // 24

typedef __attribute__((address_space(1))) const void glb_t;
typedef __attribute__((address_space(3))) void lds_t;

// ---- phase 1: per-chunk histogram over all 6 ROIs, DMA-staged ------------
__global__ __launch_bounds__(512) void hist_kernel(
    const float* __restrict__ pred, const float* __restrict__ tgt,
    const void* __restrict__ mask, int* __restrict__ ws) {
  __shared__ __align__(16) int lds[LDS_INTS];   // 52 KB
  const int tid  = threadIdx.x;
  const int lane = tid & 63;
  const int wid  = tid >> 6;            // 8 waves
  const int flat = blockIdx.x;          // 0..511
  const int b    = flat >> 7;           // patient
  const int nb   = flat & (BLKP - 1);
  const int v0   = nb * CHUNK;

  const unsigned int* mwp = (const unsigned int*)mask;
  const int byteLayout = __any(mwp[tid] > 1u);

  for (int i = tid; i < 6144; i += 512) lds[i] = 0;
  if (flat < 128 && tid < 193) {        // pre-zero dispatch-2 counters
    int zi = flat * 193 + tid;
    if (zi < ZERO_N) ws[ZERO_I + zi] = 0;
  }

  int c01 = 0, c23 = 0, c45 = 0;

  // voxel k: bits k*8 of the 6 mask dwords; bin computed once per voxel
#define VOX(SH, M, PP, GG)                                                   \
  {                                                                          \
    int a01 = (((M)[0] >> (SH)) & 1) | ((((M)[1] >> (SH)) & 1) << 16);       \
    int a23 = (((M)[2] >> (SH)) & 1) | ((((M)[3] >> (SH)) & 1) << 16);       \
    int a45 = (((M)[4] >> (SH)) & 1) | ((((M)[5] >> (SH)) & 1) << 16);       \
    int bp = min((int)((PP) * 1024.0f), NB1);                                \
    int bg = min((int)((GG) * 1024.0f), NB1);                                \
    atomicAdd(&lds[bp],        a01); atomicAdd(&lds[1024 + bp], a23);        \
    atomicAdd(&lds[2048 + bp], a45);                                         \
    atomicAdd(&lds[3072 + bg], a01); atomicAdd(&lds[4096 + bg], a23);        \
    atomicAdd(&lds[5120 + bg], a45);                                         \
    c01 += a01; c23 += a23; c45 += a45;                                      \
  }

  if (byteLayout) {
    const char* pbase = (const char*)(pred + (size_t)b * VVOX + v0);
    const char* gbase = (const char*)(tgt  + (size_t)b * VVOX + v0);
    const char* mbase = (const char*)mask;

    for (int t = 0; t < NTILE; t++) {
      // DMA 28 x 1KB slices: slots 0-7 pred, 8-15 tgt, 16-27 masks.
      // Each instr: 64 lanes x 16B -> LDS base + lane*16 (wave-uniform base).
      for (int j = wid; j < 28; j += 8) {
        const char* src;
        int dst;                         // byte offset into lds[]
        if (j < 8) {
          src = pbase + t * 8192 + j * 1024;        dst = PRED_I * 4 + j * 1024;
        } else if (j < 16) {
          src = gbase + t * 8192 + (j - 8) * 1024;  dst = TGT_I * 4 + (j - 8) * 1024;
        } else {
          int r = (j - 16) >> 1, hh = (j - 16) & 1;
          src = mbase + (size_t)(r * BPAT + b) * VVOX + v0 + t * TILE + hh * 1024;
          dst = MSK_I * 4 + r * 2048 + hh * 1024;
        }
        __builtin_amdgcn_global_load_lds(
            (glb_t*)(src + lane * 16),
            (lds_t*)((char*)lds + dst), 16, 0, 0);
      }
      __syncthreads();   // drain DMA; (iter 0) hist-zero also visible

      // process 4 voxels: this thread owns tile voxels [tid*4, tid*4+4)
      float4 pv = *(const float4*)&lds[PRED_I + tid * 4];
      float4 gv = *(const float4*)&lds[TGT_I + tid * 4];
      unsigned m[RROI];
#pragma unroll
      for (int r = 0; r < RROI; r++)
        m[r] = *(const unsigned*)&lds[MSK_I + r * 512 + tid];
      VOX(0, m, pv.x, gv.x)
      VOX(8, m, pv.y, gv.y)
      VOX(16, m, pv.z, gv.z)
      VOX(24, m, pv.w, gv.w)
      __syncthreads();   // all reads done before next tile's DMA overwrites
    }
  } else {  // int32 masks — correctness-only path, direct loads
    __syncthreads();
    const int* mi = (const int*)mask;
    const float4* p4 = (const float4*)(pred + (size_t)b * VVOX + v0);
    const float4* g4 = (const float4*)(tgt  + (size_t)b * VVOX + v0);
    for (int pk = tid; pk < CHUNK / 4; pk += 512) {
      float4 pv = p4[pk], gv = g4[pk];
      unsigned m0[RROI], m1[RROI], m2[RROI], m3[RROI];
#pragma unroll
      for (int r = 0; r < RROI; r++) {
        int4 mm = ((const int4*)(mi + (size_t)(r * BPAT + b) * VVOX + v0))[pk];
        m0[r] = mm.x; m1[r] = mm.y; m2[r] = mm.z; m3[r] = mm.w;
      }
      VOX(0, m0, pv.x, gv.x)
      VOX(0, m1, pv.y, gv.y)
      VOX(0, m2, pv.z, gv.z)
      VOX(0, m3, pv.w, gv.w)
    }
    __syncthreads();
  }
#undef VOX

  // count merge: tile buffer is free now; use its first 3 words
  if (tid < 3) lds[BUF_I + tid] = 0;
  __syncthreads();
  for (int off = 32; off > 0; off >>= 1) {
    c01 += __shfl_down(c01, off, 64);
    c23 += __shfl_down(c23, off, 64);
    c45 += __shfl_down(c45, off, 64);
  }
  if (lane == 0) {
    atomicAdd(&lds[BUF_I], c01); atomicAdd(&lds[BUF_I + 1], c23);
    atomicAdd(&lds[BUF_I + 2], c45);
  }
  __syncthreads();

  // write signed int16 diffs (pred-tgt), 2 bins per int
  for (int idx = tid; idx < RROI * HW; idx += 512) {   // 6 iters
    int r = idx >> 9, wd = idx & (HW - 1);
    int k = r >> 1, f = (r & 1) << 4;
    int b0 = 2 * wd, b1 = b0 + 1;
    int d0 = ((lds[k * 1024 + b0] >> f) & 0xffff) -
             ((lds[(3 + k) * 1024 + b0] >> f) & 0xffff);
    int d1 = ((lds[k * 1024 + b1] >> f) & 0xffff) -
             ((lds[(3 + k) * 1024 + b1] >> f) & 0xffff);
    ws[PART_I + (size_t)(flat * RROI + r) * HW + wd] = (d0 & 0xffff) | (d1 << 16);
  }
  if (tid < RROI) {
    int p = lds[BUF_I + (tid >> 1)];
    int c = (tid & 1) ? ((p >> 16) & 0xffff) : (p & 0xffff);
    ws[CNT6_I + flat * RROI + tid] = c;
  }
}

// ---- phase 2: reduce quarters -> global merge -> winner scan -> finalize -
__global__ __launch_bounds__(256) void seg_scan(int* __restrict__ ws,
                                                float* __restrict__ out) {
  const int bq  = blockIdx.x;          // 0..95
  const int seg = bq >> 2, q = bq & 3;
  const int r   = seg >> 2, b = seg & 3;
  const int t   = threadIdx.x;         // 256 threads; each owns bins 4t..4t+3

  int s[4] = {0, 0, 0, 0};
#pragma unroll 4
  for (int nb = q * 32; nb < q * 32 + 32; nb++) {
    const int2 wv = ((const int2*)(ws + PART_I +
                     (size_t)((b * BLKP + nb) * RROI + r) * HW))[t];
    s[0] += (int)(short)(wv.x & 0xffff); s[1] += wv.x >> 16;
    s[2] += (int)(short)(wv.y & 0xffff); s[3] += wv.y >> 16;
  }
  int* fh = ws + FH_I + seg * NBINS + 4 * t;
#pragma unroll
  for (int k = 0; k < 4; k++)
    if (s[k]) atomicAdd(&fh[k], s[k]);
  __threadfence();
  __shared__ int winflag;
  if (t == 0) winflag = (atomicAdd(ws + DONE_I + seg, 1) == 3);
  __syncthreads();
  if (!winflag) return;

  int bins[4];
#pragma unroll
  for (int k = 0; k < 4; k++)
    bins[k] = __hip_atomic_load(&fh[k], __ATOMIC_RELAXED,
                                __HIP_MEMORY_SCOPE_AGENT);
  int dv = (t < BLKP) ? ws[CNT6_I + (b * BLKP + t) * RROI + r] : 0;

  int tot = 0;
#pragma unroll
  for (int k = 0; k < 4; k++) { tot += bins[k]; bins[k] = tot; }
  const int lane = t & 63, wid = t >> 6;       // 4 waves
  int v = tot;
  for (int off = 1; off < 64; off <<= 1) {
    int u = __shfl_up(v, off, 64);
    if (lane >= off) v += u;
  }
  __shared__ int wsum[4]; __shared__ unsigned long long lsum[4];
  __shared__ int dsum[4];
  if (lane == 63) wsum[wid] = v;
  for (int off = 32; off > 0; off >>= 1) dv += __shfl_down(dv, off, 64);
  if (lane == 0) dsum[wid] = dv;
  __syncthreads();
  int woff = 0;
  for (int w = 0; w < wid; w++) woff += wsum[w];
  const int excl = woff + v - tot;
  unsigned long long acc = 0;
#pragma unroll
  for (int k = 0; k < 4; k++) {
    int c = excl + bins[k];
    acc += (unsigned long long)(c < 0 ? -c : c);
  }
  for (int off = 32; off > 0; off >>= 1) acc += __shfl_down(acc, off, 64);
  if (lane == 0) lsum[wid] = acc;
  __syncthreads();

  if (t == 0) {
    unsigned long long a = 0; int d = 0;
    for (int w = 0; w < 4; w++) { a += lsum[w]; d += dsum[w]; }
    ((float*)ws)[S_I + seg] = (float)((double)a * (52.0 / (double)NBINS));
    ws[DEN_I + seg] = d;
    __threadfence();
    if (atomicAdd(ws + SEGD_I, 1) == NSEG - 1) {   // last segment finalizes
      float total = 0.f; int nv = 0;
      for (int bb = 0; bb < BPAT; bb++) {
        float num = 0.f; long long dd = 0;
        for (int rr = 0; rr < RROI; rr++) {
          num += __hip_atomic_load(&((float*)ws)[S_I + rr * BPAT + bb],
                                   __ATOMIC_RELAXED, __HIP_MEMORY_SCOPE_AGENT);
          dd  += __hip_atomic_load(&ws[DEN_I + rr * BPAT + bb],
                                   __ATOMIC_RELAXED, __HIP_MEMORY_SCOPE_AGENT);
        }
        if (dd > 0) { total += num / fmaxf((float)dd, 1.f); nv++; }
      }
      out[0] = total / (float)(nv > 0 ? nv : 1);
    }
  }
}

extern "C" void kernel_launch(void* const* d_in, const int* in_sizes, int n_in,
                              void* d_out, int out_size, void* d_ws,
                              size_t ws_size, hipStream_t stream) {
  const float* pred = (const float*)d_in[0];
  const float* tgt  = (const float*)d_in[1];
  const void* mask  = d_in[2];
  int* ws = (int*)d_ws;   // needs ~6.5 MB; d_ws is 384 MiB

  hist_kernel<<<GRID1, 512, 0, stream>>>(pred, tgt, mask, ws);
  seg_scan<<<NSEG * 4, 256, 0, stream>>>(ws, (float*)d_out);
}